// Round 2
// baseline (4694.598 us; speedup 1.0000x reference)
//
#include <hip/hip_runtime.h>

typedef unsigned short u16;
typedef unsigned int   u32;
typedef __bf16  bf16x8 __attribute__((ext_vector_type(8)));
typedef float   floatx4 __attribute__((ext_vector_type(4)));

#define NP_ALL 304096
#define NP_H01 104096
#define NA_ALL 154096
#define NA_H01 54096

__device__ __forceinline__ u16 f2bf(float f){
    u32 u = __float_as_uint(f);
    return (u16)((u + 0x7fffu + ((u>>16)&1u)) >> 16);   // RNE
}

// ---------- weight-prep: f32 -> bf16 ----------
__global__ void wcvt_k(u16* __restrict__ dst, const float* __restrict__ src, int n){
    int t = blockIdx.x*256 + threadIdx.x;
    if (t < n) dst[t] = f2bf(src[t]);
}
__global__ void wadd_k(u16* __restrict__ dst, const float* __restrict__ a, const float* __restrict__ b, int n){
    int t = blockIdx.x*256 + threadIdx.x;
    if (t < n) dst[t] = f2bf(a[t] + b[t]);
}
__global__ void bias_k(float* __restrict__ dst, const float* __restrict__ a, const float* __restrict__ b, int n){
    int t = blockIdx.x*256 + threadIdx.x;
    if (t < n) dst[t] = a[t] + (b ? b[t] : 0.0f);
}
// repack bf16 W (K x N row-major) into MFMA B-fragment order:
// Wp[((kt*(N/16)+nt)*64 + lane)*8 + j] = W[kt*32 + (lane>>4)*8 + j][nt*16 + (lane&15)]
__global__ void repack_k(const u16* __restrict__ Wc, int K, int N, u16* __restrict__ Wp){
    int t = blockIdx.x*256 + threadIdx.x;
    int total = (K>>5)*(N>>4)*64;
    if (t >= total) return;
    int lane = t & 63;
    int nt = (t>>6) % (N>>4);
    int kt = (t>>6) / (N>>4);
    int n  = nt*16 + (lane & 15);
    int k0 = kt*32 + (lane>>4)*8;
    u16* dst = Wp + (size_t)t*8;
    #pragma unroll
    for (int j=0;j<8;j++) dst[j] = Wc[(size_t)(k0+j)*N + n];
}

// ---------- scatter: segment-sum + degree count via HW fp32 atomics ----------
// D = feature dim; D/2 lanes per edge, 2 dims per lane.
// BF16SRC: source features are packed bf16 (our intermediates); else f32 (inputs).
// Edges with dst >= dst_limit are dropped (their layer output is sliced away).
template<int D, bool BF16SRC>
__global__ __launch_bounds__(256) void scatter_k(
    const void* __restrict__ xsrc_, int src_ld,
    const int* __restrict__ esrc, const int* __restrict__ edst,
    int nE, int dst_limit,
    float* __restrict__ s, float* __restrict__ cnt)
{
    constexpr int L   = D/2;     // lanes per edge
    constexpr int EPB = 256/L;   // edges per block
    int e = blockIdx.x*EPB + (int)(threadIdx.x)/L;
    if (e >= nE) return;
    int lane = (int)(threadIdx.x) % L;
    int dst = edst[e];
    if (dst >= dst_limit) return;
    int src = esrc[e];
    float f0, f1;
    if (BF16SRC) {
        u32 v = *(const u32*)((const u16*)xsrc_ + (size_t)src*src_ld + 2*lane);
        f0 = __uint_as_float(v << 16);
        f1 = __uint_as_float(v & 0xFFFF0000u);
    } else {
        const float* xp = (const float*)xsrc_ + (size_t)src*src_ld + 2*lane;
        f0 = xp[0]; f1 = xp[1];
    }
    float* sp = s + (size_t)dst*D + 2*lane;
    unsafeAtomicAdd(sp,   f0);
    unsafeAtomicAdd(sp+1, f1);
    if (lane == 0) unsafeAtomicAdd(cnt + dst, 1.0f);
}

// ---------- A-matrix builders ----------
// fp32 sums -> bf16 mean columns
__global__ void mean_k(u16* __restrict__ A, int lda, int col_off,
                       const float* __restrict__ s, const float* __restrict__ cnt,
                       int M, int D){
    int t = blockIdx.x*256 + threadIdx.x;
    int half = D>>1;
    if (t >= M*half) return;
    int m = t / half, d2 = t % half;
    float rc = 1.0f / fmaxf(cnt[m], 1.0f);
    const float* sp = s + (size_t)m*D + 2*d2;
    u32 lo = f2bf(sp[0]*rc), hi = f2bf(sp[1]*rc);
    *(u32*)(A + (size_t)m*lda + col_off + 2*d2) = lo | (hi<<16);
}
// f32 feature matrix -> bf16 columns
__global__ void copyx_k(u16* __restrict__ A, int lda, int col_off,
                        const float* __restrict__ X, int xld, int M, int D){
    int t = blockIdx.x*256 + threadIdx.x;
    int half = D>>1;
    if (t >= M*half) return;
    int m = t / half, d2 = t % half;
    const float* xp = X + (size_t)m*xld + 2*d2;
    u32 lo = f2bf(xp[0]), hi = f2bf(xp[1]);
    *(u32*)(A + (size_t)m*lda + col_off + 2*d2) = lo | (hi<<16);
}

// ---------- MFMA GEMM: C[M,NT] = act(A[M,K] @ W[K,NT] + bias) ----------
// Block = 4 waves, each wave owns a 16-row tile and all NT columns.
// A from global (dwordx4/lane); B from repacked Wp (coalesced, L2-resident).
// No LDS, no barriers. M mult of 16, K mult of 32.
// F32OUT: write float32 (final output) else packed bf16.
template<int NT, bool RELU, bool F32OUT>
__global__ __launch_bounds__(256) void gemm_k(
    const u16* __restrict__ A, int lda, int M, int K,
    const u16* __restrict__ Wp, const float* __restrict__ bias,
    void* __restrict__ C_, int ldc)
{
    constexpr int NTILES = NT/16;
    int wave = threadIdx.x >> 6;
    int lane = threadIdx.x & 63;
    int tile_m = blockIdx.x*64 + wave*16;
    if (tile_m >= M) return;
    int quad = lane >> 4;
    int l15  = lane & 15;

    floatx4 acc[NTILES];
    #pragma unroll
    for (int i=0;i<NTILES;i++) acc[i] = (floatx4){0.f,0.f,0.f,0.f};

    const u16* arow = A + (size_t)(tile_m + l15)*lda + quad*8;  // A[m=lane&15][k=quad*8+j]
    int ksteps = K >> 5;
    for (int kt=0; kt<ksteps; kt++) {
        bf16x8 af = *(const bf16x8*)(arow + kt*32);
        const u16* wp = Wp + ((size_t)kt*NTILES*64 + lane)*8;
        #pragma unroll
        for (int nt=0; nt<NTILES; nt++) {
            bf16x8 bf = *(const bf16x8*)(wp + nt*64*8);
            acc[nt] = __builtin_amdgcn_mfma_f32_16x16x32_bf16(af, bf, acc[nt], 0,0,0);
        }
    }
    // D layout: col = lane&15, row = quad*4 + i
    #pragma unroll
    for (int nt=0; nt<NTILES; nt++) {
        int col = nt*16 + l15;
        float bv = bias[col];
        #pragma unroll
        for (int i=0;i<4;i++) {
            int row = tile_m + quad*4 + i;
            float v = acc[nt][i] + bv;
            if (RELU) v = fmaxf(v, 0.0f);
            if (F32OUT) ((float*)C_)[(size_t)row*ldc + col] = v;
            else        ((u16*)  C_)[(size_t)row*ldc + col] = f2bf(v);
        }
    }
}

extern "C" void kernel_launch(void* const* d_in, const int* in_sizes, int n_in,
                              void* d_out, int out_size, void* d_ws, size_t ws_size,
                              hipStream_t stream)
{
    const float* x_paper  = (const float*)d_in[0];
    const float* x_author = (const float*)d_in[1];
    const float* w_in[22];
    for (int i=0;i<22;i++) w_in[i] = (const float*)d_in[i];
    const int* e_c1 = (const int*)d_in[22]; int nE_c1 = in_sizes[22]/2;
    const int* e_c2 = (const int*)d_in[23]; int nE_c2 = in_sizes[23]/2;
    const int* e_w1 = (const int*)d_in[24]; int nE_w1 = in_sizes[24]/2;
    const int* e_w2 = (const int*)d_in[25]; int nE_w2 = in_sizes[25]/2;
    const int* e_r1 = (const int*)d_in[26]; int nE_r1 = in_sizes[26]/2;
    const int* e_r2 = (const int*)d_in[27]; int nE_r2 = in_sizes[27]/2;
    float* out = (float*)d_out;

    // ---- workspace layout (~433 MB peak, 256B-aligned) ----
    size_t off = 0;
    auto take = [&](size_t nb)->void* {
        void* p = (char*)d_ws + off;
        off = (off + nb + 255) & ~(size_t)255;
        return p;
    };
    const size_t AP_B = (size_t)NP_H01*384*2;          // 256-aligned already
    const size_t AA_B = (size_t)NA_H01*256*2;
    const size_t SB1_B = (size_t)NP_H01*256*4;
    size_t R_B = AP_B + AA_B; if (SB1_B > R_B) R_B = SB1_B;

    u16*   A1  = (u16*)  take((size_t)NP_H01*768*2); // L1 A: [mean_c1|mean_w1|xp]
    u16*   xa  = (u16*)  take((size_t)NA_H01*256*2); // L0 author output (bf16)
    float* sA  = (float*)take((size_t)NP_H01*256*4); // L0: s_c|s_w ; L1: s_c1
    void*  R   =         take(R_B);                  // L0: Ap,Aa ; L1: s_w1 then h1
    float* sB0 = (float*)take((size_t)NA_H01*128*4); // L0 rev sums
    float* cnt_all = (float*)take((size_t)(4*NP_H01 + NA_H01)*4);
    u16* Wc0p = (u16*)take((size_t)384*256*2);
    u16* Wc0a = (u16*)take((size_t)256*256*2);
    u16* Wc1  = (u16*)take((size_t)768*256*2);
    u16* Wcf  = (u16*)take((size_t)256*64*2);
    u16* Wp0p = (u16*)take((size_t)384*256*2);
    u16* Wp0a = (u16*)take((size_t)256*256*2);
    u16* Wp1  = (u16*)take((size_t)768*256*2);
    u16* Wpf  = (u16*)take((size_t)256*64*2);
    float* b0p = (float*)take(256*4);
    float* b0a = (float*)take(256*4);
    float* b1  = (float*)take(256*4);
    float* bfin= (float*)take(64*4);

    u16*   Ap  = (u16*)R;                       // L0 paper A  [mean_c|mean_w|x_p]
    u16*   Aa  = (u16*)((char*)R + AP_B);       // L0 author A [mean_r|x_a]
    float* sB1 = (float*)R;                     // L1 writes sums (after Ap/Aa dead)
    u16*   h1  = (u16*)R;                       // L1 hidden (after sB1 dead)
    float* s_w = sA + (size_t)NP_H01*128;
    float* cnt_c  = cnt_all;
    float* cnt_w  = cnt_all + NP_H01;
    float* cnt_r  = cnt_all + 2*(size_t)NP_H01;
    float* cnt_c1 = cnt_all + 2*(size_t)NP_H01 + NA_H01;
    float* cnt_w1 = cnt_all + 3*(size_t)NP_H01 + NA_H01;

    auto cdiv = [](long a, long b){ return (int)((a + b - 1)/b); };
    dim3 B(256);

    // ---- phase 1: zero L0 accumulators + all counts ----
    hipMemsetAsync(sA, 0, (size_t)NP_H01*256*4, stream);
    hipMemsetAsync(sB0, 0, (size_t)NA_H01*128*4, stream);
    hipMemsetAsync(cnt_all, 0, (size_t)(4*NP_H01 + NA_H01)*4, stream);

    // ---- weight prep (tiny) ----
    wcvt_k<<<cdiv(32768,256),B,0,stream>>>(Wc0p,        w_in[2], 32768);
    wcvt_k<<<cdiv(32768,256),B,0,stream>>>(Wc0p+32768,  w_in[5], 32768);
    wadd_k<<<cdiv(32768,256),B,0,stream>>>(Wc0p+65536,  w_in[4], w_in[7], 32768);
    wcvt_k<<<cdiv(32768,256),B,0,stream>>>(Wc0a,        w_in[8], 32768);
    wcvt_k<<<cdiv(32768,256),B,0,stream>>>(Wc0a+32768,  w_in[10], 32768);
    wcvt_k<<<cdiv(65536,256),B,0,stream>>>(Wc1,         w_in[11], 65536);
    wcvt_k<<<cdiv(65536,256),B,0,stream>>>(Wc1+65536,   w_in[14], 65536);
    wadd_k<<<cdiv(65536,256),B,0,stream>>>(Wc1+131072,  w_in[13], w_in[16], 65536);
    wcvt_k<<<cdiv(16384,256),B,0,stream>>>(Wcf,         w_in[20], 16384);
    bias_k<<<1,B,0,stream>>>(b0p, w_in[3],  w_in[6],  256);
    bias_k<<<1,B,0,stream>>>(b0a, w_in[9],  nullptr,  256);
    bias_k<<<1,B,0,stream>>>(b1,  w_in[12], w_in[15], 256);
    bias_k<<<1,B,0,stream>>>(bfin,w_in[21], nullptr,  64);
    repack_k<<<cdiv(12288,256),B,0,stream>>>(Wc0p, 384, 256, Wp0p);
    repack_k<<<cdiv( 8192,256),B,0,stream>>>(Wc0a, 256, 256, Wp0a);
    repack_k<<<cdiv(24576,256),B,0,stream>>>(Wc1,  768, 256, Wp1);
    repack_k<<<cdiv( 2048,256),B,0,stream>>>(Wcf,  256,  64, Wpf);

    // ---- phase 2: layer-0 scatters (dst-filtered, f32 sources) ----
    scatter_k<128,false><<<cdiv(nE_c1,4),B,0,stream>>>(x_paper, 128, e_c1, e_c1+nE_c1, nE_c1, NP_H01, sA,  cnt_c);
    scatter_k<128,false><<<cdiv(nE_c2,4),B,0,stream>>>(x_paper, 128, e_c2, e_c2+nE_c2, nE_c2, NP_H01, sA,  cnt_c);
    scatter_k<128,false><<<cdiv(nE_w1,4),B,0,stream>>>(x_author,128, e_w1, e_w1+nE_w1, nE_w1, NP_H01, s_w, cnt_w);
    scatter_k<128,false><<<cdiv(nE_w2,4),B,0,stream>>>(x_author,128, e_w2, e_w2+nE_w2, nE_w2, NP_H01, s_w, cnt_w);
    scatter_k<128,false><<<cdiv(nE_r1,4),B,0,stream>>>(x_paper, 128, e_r1, e_r1+nE_r1, nE_r1, NA_H01, sB0, cnt_r);
    scatter_k<128,false><<<cdiv(nE_r2,4),B,0,stream>>>(x_paper, 128, e_r2, e_r2+nE_r2, nE_r2, NA_H01, sB0, cnt_r);

    // ---- phase 3: build L0 A-matrices (bf16) ----
    int tP = NP_H01*64, tA = NA_H01*64;
    mean_k <<<cdiv(tP,256),B,0,stream>>>(Ap, 384, 0,   sA,  cnt_c, NP_H01, 128);
    mean_k <<<cdiv(tP,256),B,0,stream>>>(Ap, 384, 128, s_w, cnt_w, NP_H01, 128);
    copyx_k<<<cdiv(tP,256),B,0,stream>>>(Ap, 384, 256, x_paper, 128, NP_H01, 128);
    mean_k <<<cdiv(tA,256),B,0,stream>>>(Aa, 256, 0,   sB0, cnt_r, NA_H01, 128);
    copyx_k<<<cdiv(tA,256),B,0,stream>>>(Aa, 256, 128, x_author, 128, NA_H01, 128);

    // ---- phase 4: layer-0 GEMMs (relu fused); xp lands in A1 cols 512..767 ----
    gemm_k<256,true,false><<<cdiv(NP_H01,64),B,0,stream>>>(Ap, 384, NP_H01, 384, Wp0p, b0p, A1+512, 768);
    gemm_k<256,true,false><<<cdiv(NA_H01,64),B,0,stream>>>(Aa, 256, NA_H01, 256, Wp0a, b0a, xa, 256);

    // ---- phase 5: zero L1 accumulators (Ap/Aa now dead), layer-1 scatters ----
    hipMemsetAsync(sA, 0, (size_t)NP_H01*256*4, stream);
    hipMemsetAsync(sB1, 0, (size_t)NP_H01*256*4, stream);
    scatter_k<256,true><<<cdiv(nE_c1,2),B,0,stream>>>(A1+512, 768, e_c1, e_c1+nE_c1, nE_c1, NP_H01, sA,  cnt_c1);
    scatter_k<256,true><<<cdiv(nE_w1,2),B,0,stream>>>(xa,     256, e_w1, e_w1+nE_w1, nE_w1, NP_H01, sB1, cnt_w1);

    // ---- phase 6: build L1 mean columns ----
    int tL = NP_H01*128;
    mean_k<<<cdiv(tL,256),B,0,stream>>>(A1, 768, 0,   sA,  cnt_c1, NP_H01, 256);
    mean_k<<<cdiv(tL,256),B,0,stream>>>(A1, 768, 256, sB1, cnt_w1, NP_H01, 256);

    // ---- phase 7: layer-1 GEMM (h1 overwrites sB1 region) + final linear (f32 out) ----
    gemm_k<256,true ,false><<<cdiv(NP_H01,64),B,0,stream>>>(A1, 768, NP_H01, 768, Wp1, b1,   h1,  256);
    gemm_k<64, false,true ><<<cdiv(NP_H01,64),B,0,stream>>>(h1, 256, NP_H01, 256, Wpf, bfin, out, 64);
}

// Round 3
// 1597.186 us; speedup vs baseline: 2.9393x; 2.9393x over previous
//
#include <hip/hip_runtime.h>

typedef unsigned short u16;
typedef unsigned int   u32;
typedef __bf16  bf16x8 __attribute__((ext_vector_type(8)));
typedef float   floatx4 __attribute__((ext_vector_type(4)));

#define NP_ALL 304096
#define NP_H01 104096
#define NA_ALL 154096
#define NA_H01 54096

// CSR segment bases in the concatenated deg/rowptr array
#define SEG_C0 0
#define SEG_W0 104096
#define SEG_R0 208192
#define SEG_C1 262288
#define SEG_W1 366384
#define SCAN_N 470480
#define SCAN_NBLK 1838   // ceil(SCAN_N/256)

__device__ __forceinline__ u16 f2bf(float f){
    u32 u = __float_as_uint(f);
    return (u16)((u + 0x7fffu + ((u>>16)&1u)) >> 16);   // RNE
}
__device__ __forceinline__ float blo(u32 v){ return __uint_as_float(v<<16); }
__device__ __forceinline__ float bhi(u32 v){ return __uint_as_float(v & 0xFFFF0000u); }

// ---------- weight / feature prep ----------
__global__ void wcvt_k(u16* __restrict__ dst, const float* __restrict__ src, int n){
    int t = blockIdx.x*256 + threadIdx.x;
    if (t < n) dst[t] = f2bf(src[t]);
}
__global__ void wadd_k(u16* __restrict__ dst, const float* __restrict__ a, const float* __restrict__ b, int n){
    int t = blockIdx.x*256 + threadIdx.x;
    if (t < n) dst[t] = f2bf(a[t] + b[t]);
}
__global__ void bias_k(float* __restrict__ dst, const float* __restrict__ a, const float* __restrict__ b, int n){
    int t = blockIdx.x*256 + threadIdx.x;
    if (t < n) dst[t] = a[t] + (b ? b[t] : 0.0f);
}
// f32 pairs -> packed bf16 (one u32 per thread)
__global__ void cvt2_k(u32* __restrict__ dst, const float* __restrict__ src, int n2){
    int t = blockIdx.x*256 + threadIdx.x;
    if (t >= n2) return;
    dst[t] = (u32)f2bf(src[2*t]) | ((u32)f2bf(src[2*t+1])<<16);
}
// repack bf16 W (K x N row-major) into MFMA B-fragment order
__global__ void repack_k(const u16* __restrict__ Wc, int K, int N, u16* __restrict__ Wp){
    int t = blockIdx.x*256 + threadIdx.x;
    int total = (K>>5)*(N>>4)*64;
    if (t >= total) return;
    int lane = t & 63;
    int nt = (t>>6) % (N>>4);
    int kt = (t>>6) / (N>>4);
    int n  = nt*16 + (lane & 15);
    int k0 = kt*32 + (lane>>4)*8;
    u16* dst = Wp + (size_t)t*8;
    #pragma unroll
    for (int j=0;j<8;j++) dst[j] = Wc[(size_t)(k0+j)*N + n];
}

// ---------- CSR build ----------
__global__ void hist_k(const int* __restrict__ edst, int nE, int limit, int* __restrict__ deg){
    int t = blockIdx.x*256 + threadIdx.x;
    if (t >= nE) return;
    int d = edst[t];
    if (d < limit) atomicAdd(deg + d, 1);
}
__global__ void scan1_k(const int* __restrict__ deg, int* __restrict__ bsum){
    __shared__ int sm[256];
    int t = blockIdx.x*256 + threadIdx.x;
    sm[threadIdx.x] = (t < SCAN_N) ? deg[t] : 0;
    __syncthreads();
    for (int s=128; s>0; s>>=1){
        if (threadIdx.x < s) sm[threadIdx.x] += sm[threadIdx.x+s];
        __syncthreads();
    }
    if (threadIdx.x == 0) bsum[blockIdx.x] = sm[0];
}
__global__ void scan2_k(int* __restrict__ bsum, int n){
    __shared__ int sm[256];
    int chunk = (n + 255) >> 8;
    int st = threadIdx.x * chunk;
    int sum = 0;
    for (int i=0;i<chunk;i++){ int idx = st+i; if (idx < n) sum += bsum[idx]; }
    sm[threadIdx.x] = sum; __syncthreads();
    int acc = sum;
    for (int s=1; s<256; s<<=1){
        int t2 = (threadIdx.x >= s) ? sm[threadIdx.x - s] : 0;
        __syncthreads();
        acc += t2; sm[threadIdx.x] = acc;
        __syncthreads();
    }
    int excl = acc - sum;
    for (int i=0;i<chunk;i++){
        int idx = st+i;
        if (idx < n){ int v = bsum[idx]; bsum[idx] = excl; excl += v; }
    }
}
__global__ void scan3_k(const int* __restrict__ deg, const int* __restrict__ bsum,
                        int* __restrict__ rowptr, int* __restrict__ wp){
    __shared__ int sm[256];
    int t = blockIdx.x*256 + threadIdx.x;
    int v = (t < SCAN_N) ? deg[t] : 0;
    sm[threadIdx.x] = v; __syncthreads();
    int acc = v;
    for (int s=1; s<256; s<<=1){
        int t2 = (threadIdx.x >= s) ? sm[threadIdx.x - s] : 0;
        __syncthreads();
        acc += t2; sm[threadIdx.x] = acc;
        __syncthreads();
    }
    int excl = acc - v + bsum[blockIdx.x];
    if (t < SCAN_N){ rowptr[t] = excl; wp[t] = excl; }
    if (t == SCAN_N-1) rowptr[SCAN_N] = excl + v;
}
__global__ void fill_k(const int* __restrict__ esrc, const int* __restrict__ edst,
                       int nE, int limit, int* __restrict__ wp, int* __restrict__ pool){
    int t = blockIdx.x*256 + threadIdx.x;
    if (t >= nE) return;
    int d = edst[t];
    if (d >= limit) return;
    int p = atomicAdd(wp + d, 1);
    pool[p] = esrc[t];
}

// ---------- gather: mean over in-edges, bf16 sources, bf16 output row ----------
// D=128: lane covers 2 dims (u32 load); D=256: lane covers 4 dims (uint2 load).
template<int D>
__device__ __forceinline__ void gather_mean(
    const u16* __restrict__ src, int ld,
    const int* __restrict__ rowptr, int seg, int d,
    const int* __restrict__ pool, int lane, u16* __restrict__ outrow)
{
    int b = rowptr[seg + d], e = rowptr[seg + d + 1];
    float rc = 1.0f / (float)((e - b) > 1 ? (e - b) : 1);
    if (D == 128) {
        float a0=0,a1=0,c0=0,c1=0;
        int i = b;
        for (; i+1 < e; i += 2){
            int s0 = pool[i], s1 = pool[i+1];
            u32 v0 = *(const u32*)(src + (size_t)s0*ld + 2*lane);
            u32 v1 = *(const u32*)(src + (size_t)s1*ld + 2*lane);
            a0 += blo(v0); a1 += bhi(v0);
            c0 += blo(v1); c1 += bhi(v1);
        }
        if (i < e){
            int s0 = pool[i];
            u32 v0 = *(const u32*)(src + (size_t)s0*ld + 2*lane);
            a0 += blo(v0); a1 += bhi(v0);
        }
        u32 lo = f2bf((a0+c0)*rc), hi = f2bf((a1+c1)*rc);
        *(u32*)(outrow + 2*lane) = lo | (hi<<16);
    } else {
        float a0=0,a1=0,a2=0,a3=0,c0=0,c1=0,c2=0,c3=0;
        int i = b;
        for (; i+1 < e; i += 2){
            int s0 = pool[i], s1 = pool[i+1];
            uint2 v0 = *(const uint2*)(src + (size_t)s0*ld + 4*lane);
            uint2 v1 = *(const uint2*)(src + (size_t)s1*ld + 4*lane);
            a0 += blo(v0.x); a1 += bhi(v0.x); a2 += blo(v0.y); a3 += bhi(v0.y);
            c0 += blo(v1.x); c1 += bhi(v1.x); c2 += blo(v1.y); c3 += bhi(v1.y);
        }
        if (i < e){
            int s0 = pool[i];
            uint2 v0 = *(const uint2*)(src + (size_t)s0*ld + 4*lane);
            a0 += blo(v0.x); a1 += bhi(v0.x); a2 += blo(v0.y); a3 += bhi(v0.y);
        }
        uint2 o;
        o.x = (u32)f2bf((a0+c0)*rc) | ((u32)f2bf((a1+c1)*rc)<<16);
        o.y = (u32)f2bf((a2+c2)*rc) | ((u32)f2bf((a3+c3)*rc)<<16);
        *(uint2*)(outrow + 4*lane) = o;
    }
}

// L0 paper: Ap[d] = [mean_cites | mean_writes | x_paper[d]]  (384 cols)
__global__ __launch_bounds__(256) void gAp_k(
    const u16* __restrict__ xpb, const u16* __restrict__ xab,
    const int* __restrict__ rowptr, const int* __restrict__ pool,
    u16* __restrict__ Ap)
{
    int gid = blockIdx.x*256 + threadIdx.x;
    int wid = gid >> 6, lane = gid & 63;
    if (wid >= NP_H01) return;
    u16* row = Ap + (size_t)wid*384;
    gather_mean<128>(xpb, 128, rowptr, SEG_C0, wid, pool, lane, row);
    gather_mean<128>(xab, 128, rowptr, SEG_W0, wid, pool, lane, row + 128);
    *(u32*)(row + 256 + 2*lane) = *(const u32*)(xpb + (size_t)wid*128 + 2*lane);
}
// L0 author: Aa[d] = [mean_rev | x_author[d]]  (256 cols)
__global__ __launch_bounds__(256) void gAa_k(
    const u16* __restrict__ xpb, const u16* __restrict__ xab,
    const int* __restrict__ rowptr, const int* __restrict__ pool,
    u16* __restrict__ Aa)
{
    int gid = blockIdx.x*256 + threadIdx.x;
    int wid = gid >> 6, lane = gid & 63;
    if (wid >= NA_H01) return;
    u16* row = Aa + (size_t)wid*256;
    gather_mean<128>(xpb, 128, rowptr, SEG_R0, wid, pool, lane, row);
    *(u32*)(row + 128 + 2*lane) = *(const u32*)(xab + (size_t)wid*128 + 2*lane);
}
// L1: A1[d] cols 0..511 = [mean_c1(xp) | mean_w1(xa)]; cols 512..767 = xp (already there)
__global__ __launch_bounds__(256) void gA1_k(
    const u16* __restrict__ xp, const u16* __restrict__ xa,
    const int* __restrict__ rowptr, const int* __restrict__ pool,
    u16* __restrict__ A1)
{
    int gid = blockIdx.x*256 + threadIdx.x;
    int wid = gid >> 6, lane = gid & 63;
    if (wid >= NP_H01) return;
    u16* row = A1 + (size_t)wid*768;
    gather_mean<256>(xp, 768, rowptr, SEG_C1, wid, pool, lane, row);
    gather_mean<256>(xa, 256, rowptr, SEG_W1, wid, pool, lane, row + 256);
}

// ---------- MFMA GEMM: C[M,NT] = act(A[M,K] @ W[K,NT] + bias) ----------
template<int NT, bool RELU, bool F32OUT>
__global__ __launch_bounds__(256) void gemm_k(
    const u16* __restrict__ A, int lda, int M, int K,
    const u16* __restrict__ Wp, const float* __restrict__ bias,
    void* __restrict__ C_, int ldc)
{
    constexpr int NTILES = NT/16;
    int wave = threadIdx.x >> 6;
    int lane = threadIdx.x & 63;
    int tile_m = blockIdx.x*64 + wave*16;
    if (tile_m >= M) return;
    int quad = lane >> 4;
    int l15  = lane & 15;

    floatx4 acc[NTILES];
    #pragma unroll
    for (int i=0;i<NTILES;i++) acc[i] = (floatx4){0.f,0.f,0.f,0.f};

    const u16* arow = A + (size_t)(tile_m + l15)*lda + quad*8;
    int ksteps = K >> 5;
    for (int kt=0; kt<ksteps; kt++) {
        bf16x8 af = *(const bf16x8*)(arow + kt*32);
        const u16* wp = Wp + ((size_t)kt*NTILES*64 + lane)*8;
        #pragma unroll
        for (int nt=0; nt<NTILES; nt++) {
            bf16x8 bf = *(const bf16x8*)(wp + nt*64*8);
            acc[nt] = __builtin_amdgcn_mfma_f32_16x16x32_bf16(af, bf, acc[nt], 0,0,0);
        }
    }
    #pragma unroll
    for (int nt=0; nt<NTILES; nt++) {
        int col = nt*16 + l15;
        float bv = bias[col];
        #pragma unroll
        for (int i=0;i<4;i++) {
            int row = tile_m + quad*4 + i;
            float v = acc[nt][i] + bv;
            if (RELU) v = fmaxf(v, 0.0f);
            if (F32OUT) ((float*)C_)[(size_t)row*ldc + col] = v;
            else        ((u16*)  C_)[(size_t)row*ldc + col] = f2bf(v);
        }
    }
}

extern "C" void kernel_launch(void* const* d_in, const int* in_sizes, int n_in,
                              void* d_out, int out_size, void* d_ws, size_t ws_size,
                              hipStream_t stream)
{
    const float* x_paper  = (const float*)d_in[0];
    const float* x_author = (const float*)d_in[1];
    const float* w_in[22];
    for (int i=0;i<22;i++) w_in[i] = (const float*)d_in[i];
    const int* e_c1 = (const int*)d_in[22]; int nE_c1 = in_sizes[22]/2;
    const int* e_c2 = (const int*)d_in[23]; int nE_c2 = in_sizes[23]/2;
    const int* e_w1 = (const int*)d_in[24]; int nE_w1 = in_sizes[24]/2;
    const int* e_w2 = (const int*)d_in[25]; int nE_w2 = in_sizes[25]/2;
    const int* e_r1 = (const int*)d_in[26]; int nE_r1 = in_sizes[26]/2;
    const int* e_r2 = (const int*)d_in[27]; int nE_r2 = in_sizes[27]/2;
    float* out = (float*)d_out;

    // ---- workspace layout (~320 MB peak) ----
    size_t off = 0;
    auto take = [&](size_t nb)->void* {
        void* p = (char*)d_ws + off;
        off = (off + nb + 255) & ~(size_t)255;
        return p;
    };
    u16*   A1  = (u16*)take((size_t)NP_H01*768*2); // L1 A; early life: xpb|xab overlay
    u16*   xa  = (u16*)take((size_t)NA_H01*256*2); // L0 author output (bf16)
    u16*   Ap  = (u16*)take((size_t)NP_H01*384*2); // L0 paper A; later h1 overlay
    u16*   Aa  = (u16*)take((size_t)NA_H01*256*2); // L0 author A
    int*   deg    = (int*)take((size_t)SCAN_N*4);
    int*   rowptr = (int*)take((size_t)(SCAN_N+1)*4);
    int*   wp     = (int*)take((size_t)SCAN_N*4);
    int*   bsum   = (int*)take((size_t)SCAN_NBLK*4);
    int*   pool   = (int*)take((size_t)4000000*4);
    u16* Wc0p = (u16*)take((size_t)384*256*2);
    u16* Wc0a = (u16*)take((size_t)256*256*2);
    u16* Wc1  = (u16*)take((size_t)768*256*2);
    u16* Wcf  = (u16*)take((size_t)256*64*2);
    u16* Wp0p = (u16*)take((size_t)384*256*2);
    u16* Wp0a = (u16*)take((size_t)256*256*2);
    u16* Wp1  = (u16*)take((size_t)768*256*2);
    u16* Wpf  = (u16*)take((size_t)256*64*2);
    float* b0p = (float*)take(256*4);
    float* b0a = (float*)take(256*4);
    float* b1  = (float*)take(256*4);
    float* bfin= (float*)take(64*4);

    // overlays:
    u16* xpb = A1;                                   // bf16 x_paper  (NP_ALL x 128), dead before L0 GEMM writes A1
    u16* xab = A1 + (size_t)NP_ALL*128;              // bf16 x_author (NA_ALL x 128), dead before L0 GEMM writes A1
    u16* h1  = Ap;                                   // L1 hidden, Ap dead after L0 GEMM

    auto cdiv = [](long a, long b){ return (int)((a + b - 1)/b); };
    dim3 B(256);

    // ---- phase 0: zero CSR histogram ----
    hipMemsetAsync(deg, 0, (size_t)SCAN_N*4, stream);

    // ---- phase 1: weight + feature prep ----
    wcvt_k<<<cdiv(32768,256),B,0,stream>>>(Wc0p,        w_in[2], 32768);
    wcvt_k<<<cdiv(32768,256),B,0,stream>>>(Wc0p+32768,  w_in[5], 32768);
    wadd_k<<<cdiv(32768,256),B,0,stream>>>(Wc0p+65536,  w_in[4], w_in[7], 32768);
    wcvt_k<<<cdiv(32768,256),B,0,stream>>>(Wc0a,        w_in[8], 32768);
    wcvt_k<<<cdiv(32768,256),B,0,stream>>>(Wc0a+32768,  w_in[10], 32768);
    wcvt_k<<<cdiv(65536,256),B,0,stream>>>(Wc1,         w_in[11], 65536);
    wcvt_k<<<cdiv(65536,256),B,0,stream>>>(Wc1+65536,   w_in[14], 65536);
    wadd_k<<<cdiv(65536,256),B,0,stream>>>(Wc1+131072,  w_in[13], w_in[16], 65536);
    wcvt_k<<<cdiv(16384,256),B,0,stream>>>(Wcf,         w_in[20], 16384);
    bias_k<<<1,B,0,stream>>>(b0p, w_in[3],  w_in[6],  256);
    bias_k<<<1,B,0,stream>>>(b0a, w_in[9],  nullptr,  256);
    bias_k<<<1,B,0,stream>>>(b1,  w_in[12], w_in[15], 256);
    bias_k<<<1,B,0,stream>>>(bfin,w_in[21], nullptr,  64);
    repack_k<<<cdiv(12288,256),B,0,stream>>>(Wc0p, 384, 256, Wp0p);
    repack_k<<<cdiv( 8192,256),B,0,stream>>>(Wc0a, 256, 256, Wp0a);
    repack_k<<<cdiv(24576,256),B,0,stream>>>(Wc1,  768, 256, Wp1);
    repack_k<<<cdiv( 2048,256),B,0,stream>>>(Wcf,  256,  64, Wpf);
    int n2p = NP_ALL*128/2, n2a = NA_ALL*128/2;
    cvt2_k<<<cdiv(n2p,256),B,0,stream>>>((u32*)xpb, x_paper,  n2p);
    cvt2_k<<<cdiv(n2a,256),B,0,stream>>>((u32*)xab, x_author, n2a);

    // ---- phase 2: CSR build (histogram -> scan -> fill) ----
    hist_k<<<cdiv(nE_c1,256),B,0,stream>>>(e_c1+nE_c1, nE_c1, NP_H01, deg+SEG_C0);
    hist_k<<<cdiv(nE_c2,256),B,0,stream>>>(e_c2+nE_c2, nE_c2, NP_H01, deg+SEG_C0);
    hist_k<<<cdiv(nE_w1,256),B,0,stream>>>(e_w1+nE_w1, nE_w1, NP_H01, deg+SEG_W0);
    hist_k<<<cdiv(nE_w2,256),B,0,stream>>>(e_w2+nE_w2, nE_w2, NP_H01, deg+SEG_W0);
    hist_k<<<cdiv(nE_r1,256),B,0,stream>>>(e_r1+nE_r1, nE_r1, NA_H01, deg+SEG_R0);
    hist_k<<<cdiv(nE_r2,256),B,0,stream>>>(e_r2+nE_r2, nE_r2, NA_H01, deg+SEG_R0);
    hist_k<<<cdiv(nE_c1,256),B,0,stream>>>(e_c1+nE_c1, nE_c1, NP_H01, deg+SEG_C1);
    hist_k<<<cdiv(nE_w1,256),B,0,stream>>>(e_w1+nE_w1, nE_w1, NP_H01, deg+SEG_W1);
    scan1_k<<<SCAN_NBLK,B,0,stream>>>(deg, bsum);
    scan2_k<<<1,B,0,stream>>>(bsum, SCAN_NBLK);
    scan3_k<<<SCAN_NBLK,B,0,stream>>>(deg, bsum, rowptr, wp);
    fill_k<<<cdiv(nE_c1,256),B,0,stream>>>(e_c1, e_c1+nE_c1, nE_c1, NP_H01, wp+SEG_C0, pool);
    fill_k<<<cdiv(nE_c2,256),B,0,stream>>>(e_c2, e_c2+nE_c2, nE_c2, NP_H01, wp+SEG_C0, pool);
    fill_k<<<cdiv(nE_w1,256),B,0,stream>>>(e_w1, e_w1+nE_w1, nE_w1, NP_H01, wp+SEG_W0, pool);
    fill_k<<<cdiv(nE_w2,256),B,0,stream>>>(e_w2, e_w2+nE_w2, nE_w2, NP_H01, wp+SEG_W0, pool);
    fill_k<<<cdiv(nE_r1,256),B,0,stream>>>(e_r1, e_r1+nE_r1, nE_r1, NA_H01, wp+SEG_R0, pool);
    fill_k<<<cdiv(nE_r2,256),B,0,stream>>>(e_r2, e_r2+nE_r2, nE_r2, NA_H01, wp+SEG_R0, pool);
    fill_k<<<cdiv(nE_c1,256),B,0,stream>>>(e_c1, e_c1+nE_c1, nE_c1, NP_H01, wp+SEG_C1, pool);
    fill_k<<<cdiv(nE_w1,256),B,0,stream>>>(e_w1, e_w1+nE_w1, nE_w1, NP_H01, wp+SEG_W1, pool);

    // ---- phase 3: L0 gathers (build Ap, Aa) ----
    gAp_k<<<cdiv((long)NP_H01*64,256),B,0,stream>>>(xpb, xab, rowptr, pool, Ap);
    gAa_k<<<cdiv((long)NA_H01*64,256),B,0,stream>>>(xpb, xab, rowptr, pool, Aa);

    // ---- phase 4: L0 GEMMs (xpb/xab dead now; xp lands in A1 cols 512..767) ----
    gemm_k<256,true,false><<<cdiv(NP_H01,64),B,0,stream>>>(Ap, 384, NP_H01, 384, Wp0p, b0p, A1+512, 768);
    gemm_k<256,true,false><<<cdiv(NA_H01,64),B,0,stream>>>(Aa, 256, NA_H01, 256, Wp0a, b0a, xa, 256);

    // ---- phase 5: L1 gather (A1 cols 0..511) ----
    gA1_k<<<cdiv((long)NP_H01*64,256),B,0,stream>>>(A1+512, xa, rowptr, pool, A1);

    // ---- phase 6: L1 GEMM (h1 overlays Ap) + final linear (f32 out) ----
    gemm_k<256,true ,false><<<cdiv(NP_H01,64),B,0,stream>>>(A1, 768, NP_H01, 768, Wp1, b1,   h1,  256);
    gemm_k<64, false,true ><<<cdiv(NP_H01,64),B,0,stream>>>(h1, 256, NP_H01, 256, Wpf, bfin, out, 64);
}

// Round 4
// 1253.052 us; speedup vs baseline: 3.7465x; 1.2746x over previous
//
#include <hip/hip_runtime.h>

typedef unsigned short u16;
typedef unsigned int   u32;
typedef __bf16  bf16x8 __attribute__((ext_vector_type(8)));
typedef float   floatx4 __attribute__((ext_vector_type(4)));

#define NP_ALL 304096
#define NP_H01 104096
#define NA_ALL 154096
#define NA_H01 54096

// CSR segment bases in the concatenated deg/rowptr array
#define SEG_C0 0
#define SEG_W0 104096
#define SEG_R0 208192
#define SEG_C1 262288
#define SEG_W1 366384
#define SCAN_N 470480
#define SCAN_NBLK 1838   // ceil(SCAN_N/256)

__device__ __forceinline__ u16 f2bf(float f){
    u32 u = __float_as_uint(f);
    return (u16)((u + 0x7fffu + ((u>>16)&1u)) >> 16);   // RNE
}
__device__ __forceinline__ float blo(u32 v){ return __uint_as_float(v<<16); }
__device__ __forceinline__ float bhi(u32 v){ return __uint_as_float(v & 0xFFFF0000u); }

// ---------- weight / feature prep ----------
__global__ void wcvt_k(u16* __restrict__ dst, const float* __restrict__ src, int n){
    int t = blockIdx.x*256 + threadIdx.x;
    if (t < n) dst[t] = f2bf(src[t]);
}
__global__ void wadd_k(u16* __restrict__ dst, const float* __restrict__ a, const float* __restrict__ b, int n){
    int t = blockIdx.x*256 + threadIdx.x;
    if (t < n) dst[t] = f2bf(a[t] + b[t]);
}
__global__ void bias_k(float* __restrict__ dst, const float* __restrict__ a, const float* __restrict__ b, int n){
    int t = blockIdx.x*256 + threadIdx.x;
    if (t < n) dst[t] = a[t] + (b ? b[t] : 0.0f);
}
// f32 pairs -> packed bf16 (one u32 per thread)
__global__ void cvt2_k(u32* __restrict__ dst, const float* __restrict__ src, int n2){
    int t = blockIdx.x*256 + threadIdx.x;
    if (t >= n2) return;
    dst[t] = (u32)f2bf(src[2*t]) | ((u32)f2bf(src[2*t+1])<<16);
}
// repack bf16 W (K x N row-major) into MFMA B-fragment order
__global__ void repack_k(const u16* __restrict__ Wc, int K, int N, u16* __restrict__ Wp){
    int t = blockIdx.x*256 + threadIdx.x;
    int total = (K>>5)*(N>>4)*64;
    if (t >= total) return;
    int lane = t & 63;
    int nt = (t>>6) % (N>>4);
    int kt = (t>>6) / (N>>4);
    int n  = nt*16 + (lane & 15);
    int k0 = kt*32 + (lane>>4)*8;
    u16* dst = Wp + (size_t)t*8;
    #pragma unroll
    for (int j=0;j<8;j++) dst[j] = Wc[(size_t)(k0+j)*N + n];
}

// ---------- CSR build ----------
__global__ void hist_k(const int* __restrict__ edst, int nE, int limit, int* __restrict__ deg){
    int t = blockIdx.x*256 + threadIdx.x;
    if (t >= nE) return;
    int d = edst[t];
    if (d < limit) atomicAdd(deg + d, 1);
}
__global__ void scan1_k(const int* __restrict__ deg, int* __restrict__ bsum){
    __shared__ int sm[256];
    int t = blockIdx.x*256 + threadIdx.x;
    sm[threadIdx.x] = (t < SCAN_N) ? deg[t] : 0;
    __syncthreads();
    for (int s=128; s>0; s>>=1){
        if (threadIdx.x < s) sm[threadIdx.x] += sm[threadIdx.x+s];
        __syncthreads();
    }
    if (threadIdx.x == 0) bsum[blockIdx.x] = sm[0];
}
__global__ void scan2_k(int* __restrict__ bsum, int n){
    __shared__ int sm[256];
    int chunk = (n + 255) >> 8;
    int st = threadIdx.x * chunk;
    int sum = 0;
    for (int i=0;i<chunk;i++){ int idx = st+i; if (idx < n) sum += bsum[idx]; }
    sm[threadIdx.x] = sum; __syncthreads();
    int acc = sum;
    for (int s=1; s<256; s<<=1){
        int t2 = (threadIdx.x >= s) ? sm[threadIdx.x - s] : 0;
        __syncthreads();
        acc += t2; sm[threadIdx.x] = acc;
        __syncthreads();
    }
    int excl = acc - sum;
    for (int i=0;i<chunk;i++){
        int idx = st+i;
        if (idx < n){ int v = bsum[idx]; bsum[idx] = excl; excl += v; }
    }
}
__global__ void scan3_k(const int* __restrict__ deg, const int* __restrict__ bsum,
                        int* __restrict__ rowptr, int* __restrict__ wp){
    __shared__ int sm[256];
    int t = blockIdx.x*256 + threadIdx.x;
    int v = (t < SCAN_N) ? deg[t] : 0;
    sm[threadIdx.x] = v; __syncthreads();
    int acc = v;
    for (int s=1; s<256; s<<=1){
        int t2 = (threadIdx.x >= s) ? sm[threadIdx.x - s] : 0;
        __syncthreads();
        acc += t2; sm[threadIdx.x] = acc;
        __syncthreads();
    }
    int excl = acc - v + bsum[blockIdx.x];
    if (t < SCAN_N){ rowptr[t] = excl; wp[t] = excl; }
    if (t == SCAN_N-1) rowptr[SCAN_N] = excl + v;
}
__global__ void fill_k(const int* __restrict__ esrc, const int* __restrict__ edst,
                       int nE, int limit, int* __restrict__ wp, int* __restrict__ pool){
    int t = blockIdx.x*256 + threadIdx.x;
    if (t >= nE) return;
    int d = edst[t];
    if (d >= limit) return;
    int p = atomicAdd(wp + d, 1);
    pool[p] = esrc[t];
}

// ---------- gather: mean over in-edges, bf16 sources, bf16 output row ----------
template<int D>
__device__ __forceinline__ void gather_mean(
    const u16* __restrict__ src, int ld,
    const int* __restrict__ rowptr, int seg, int d,
    const int* __restrict__ pool, int lane, u16* __restrict__ outrow)
{
    int b = rowptr[seg + d], e = rowptr[seg + d + 1];
    float rc = 1.0f / (float)((e - b) > 1 ? (e - b) : 1);
    if (D == 128) {
        float a0=0,a1=0,c0=0,c1=0;
        int i = b;
        for (; i+1 < e; i += 2){
            int s0 = pool[i], s1 = pool[i+1];
            u32 v0 = *(const u32*)(src + (size_t)s0*ld + 2*lane);
            u32 v1 = *(const u32*)(src + (size_t)s1*ld + 2*lane);
            a0 += blo(v0); a1 += bhi(v0);
            c0 += blo(v1); c1 += bhi(v1);
        }
        if (i < e){
            int s0 = pool[i];
            u32 v0 = *(const u32*)(src + (size_t)s0*ld + 2*lane);
            a0 += blo(v0); a1 += bhi(v0);
        }
        u32 lo = f2bf((a0+c0)*rc), hi = f2bf((a1+c1)*rc);
        *(u32*)(outrow + 2*lane) = lo | (hi<<16);
    } else {
        float a0=0,a1=0,a2=0,a3=0,c0=0,c1=0,c2=0,c3=0;
        int i = b;
        for (; i+1 < e; i += 2){
            int s0 = pool[i], s1 = pool[i+1];
            uint2 v0 = *(const uint2*)(src + (size_t)s0*ld + 4*lane);
            uint2 v1 = *(const uint2*)(src + (size_t)s1*ld + 4*lane);
            a0 += blo(v0.x); a1 += bhi(v0.x); a2 += blo(v0.y); a3 += bhi(v0.y);
            c0 += blo(v1.x); c1 += bhi(v1.x); c2 += blo(v1.y); c3 += bhi(v1.y);
        }
        if (i < e){
            int s0 = pool[i];
            uint2 v0 = *(const uint2*)(src + (size_t)s0*ld + 4*lane);
            a0 += blo(v0.x); a1 += bhi(v0.x); a2 += blo(v0.y); a3 += bhi(v0.y);
        }
        uint2 o;
        o.x = (u32)f2bf((a0+c0)*rc) | ((u32)f2bf((a1+c1)*rc)<<16);
        o.y = (u32)f2bf((a2+c2)*rc) | ((u32)f2bf((a3+c3)*rc)<<16);
        *(uint2*)(outrow + 4*lane) = o;
    }
}

// L0 paper: Ap[d] = [mean_cites | mean_writes | x_paper[d]]  (384 cols)
__global__ __launch_bounds__(256) void gAp_k(
    const u16* __restrict__ xpb, const u16* __restrict__ xab,
    const int* __restrict__ rowptr, const int* __restrict__ pool,
    u16* __restrict__ Ap)
{
    int gid = blockIdx.x*256 + threadIdx.x;
    int wid = gid >> 6, lane = gid & 63;
    if (wid >= NP_H01) return;
    u16* row = Ap + (size_t)wid*384;
    gather_mean<128>(xpb, 128, rowptr, SEG_C0, wid, pool, lane, row);
    gather_mean<128>(xab, 128, rowptr, SEG_W0, wid, pool, lane, row + 128);
    *(u32*)(row + 256 + 2*lane) = *(const u32*)(xpb + (size_t)wid*128 + 2*lane);
}
// L0 author: Aa[d] = [mean_rev | x_author[d]]  (256 cols)
__global__ __launch_bounds__(256) void gAa_k(
    const u16* __restrict__ xpb, const u16* __restrict__ xab,
    const int* __restrict__ rowptr, const int* __restrict__ pool,
    u16* __restrict__ Aa)
{
    int gid = blockIdx.x*256 + threadIdx.x;
    int wid = gid >> 6, lane = gid & 63;
    if (wid >= NA_H01) return;
    u16* row = Aa + (size_t)wid*256;
    gather_mean<128>(xpb, 128, rowptr, SEG_R0, wid, pool, lane, row);
    *(u32*)(row + 128 + 2*lane) = *(const u32*)(xab + (size_t)wid*128 + 2*lane);
}
// L1: A1[d] cols 0..511 = [mean_c1(xp) | mean_w1(xa)]; cols 512..767 = xp
__global__ __launch_bounds__(256) void gA1_k(
    const u16* __restrict__ xp, const u16* __restrict__ xa,
    const int* __restrict__ rowptr, const int* __restrict__ pool,
    u16* __restrict__ A1)
{
    int gid = blockIdx.x*256 + threadIdx.x;
    int wid = gid >> 6, lane = gid & 63;
    if (wid >= NP_H01) return;
    u16* row = A1 + (size_t)wid*768;
    gather_mean<256>(xp, 768, rowptr, SEG_C1, wid, pool, lane, row);
    gather_mean<256>(xa, 256, rowptr, SEG_W1, wid, pool, lane, row + 256);
}

// ---------- MFMA GEMM v2: LDS-staged B (global_load_lds), register-blocked ----------
// Block = 4 waves arranged WROWS x WCOLS; each wave computes WMT x WNT 16x16 tiles.
// Block tile: BM = WROWS*WMT*16 rows, BN = WCOLS*WNT*16 cols (grid.y covers N/BN).
// K consumed in BK=64 stages (2 MFMA kt per stage); B staged to LDS via
// global_load_lds width=16 (m97 2-barrier structure); A direct global per-lane rows.
template<int WROWS, int WCOLS, int WMT, int WNT, bool RELU, bool F32OUT>
__global__ __launch_bounds__(256) void gemm2_k(
    const u16* __restrict__ A, int lda, int M, int K,
    const u16* __restrict__ Wp, int nt16, const float* __restrict__ bias,
    void* __restrict__ C_, int ldc)
{
    constexpr int BNT  = WCOLS*WNT;      // n-tiles per block
    constexpr int BM   = WROWS*WMT*16;
    constexpr int NSTG = 2*BNT;          // frag-groups (1 KB each) per BK=64 stage
    constexpr int PERW = NSTG/4;
    __shared__ __align__(16) u16 ldsB[NSTG*512];

    int wave = threadIdx.x >> 6, lane = threadIdx.x & 63;
    int quad = lane >> 4, l15 = lane & 15;
    int wr = wave / WCOLS, wc = wave % WCOLS;
    int bm0 = blockIdx.x * BM;
    int ntb = blockIdx.y * BNT;

    floatx4 acc[WMT][WNT];
    #pragma unroll
    for (int i=0;i<WMT;i++)
        #pragma unroll
        for (int j=0;j<WNT;j++) acc[i][j] = (floatx4){0.f,0.f,0.f,0.f};

    int rowb[WMT];                       // clamped row indices for A loads
    #pragma unroll
    for (int i=0;i<WMT;i++){
        int r = bm0 + (wr*WMT + i)*16 + l15;
        rowb[i] = (r < M) ? r : (M-1);
    }

    int nstages = K >> 6;
    for (int s=0; s<nstages; s++){
        int kt0 = s*2;
        if (s) __syncthreads();          // prior-stage LDS reads complete
        #pragma unroll
        for (int i=0;i<PERW;i++){
            int g = wave*PERW + i;
            int ktl = g / BNT, ntl = g % BNT;
            const u16* gp = Wp + ((size_t)(kt0+ktl)*nt16 + ntb + ntl)*512 + lane*8;
            u16* lp = ldsB + g*512 + lane*8;
            __builtin_amdgcn_global_load_lds(
                (const __attribute__((address_space(1))) void*)gp,
                (__attribute__((address_space(3))) void*)lp, 16, 0, 0);
        }
        __syncthreads();                 // staging drained (vmcnt(0) before barrier)
        #pragma unroll
        for (int ktl=0; ktl<2; ktl++){
            int kt = kt0 + ktl;
            bf16x8 af[WMT];
            #pragma unroll
            for (int i=0;i<WMT;i++)
                af[i] = *(const bf16x8*)(A + (size_t)rowb[i]*lda + kt*32 + quad*8);
            bf16x8 bfr[WNT];
            #pragma unroll
            for (int j=0;j<WNT;j++)
                bfr[j] = *(const bf16x8*)(ldsB + ((size_t)(ktl*BNT + wc*WNT + j)*64 + lane)*8);
            #pragma unroll
            for (int i=0;i<WMT;i++)
                #pragma unroll
                for (int j=0;j<WNT;j++)
                    acc[i][j] = __builtin_amdgcn_mfma_f32_16x16x32_bf16(af[i], bfr[j], acc[i][j], 0,0,0);
        }
    }
    // epilogue: D layout col=lane&15, row=quad*4+ii
    #pragma unroll
    for (int j=0;j<WNT;j++){
        int col = (ntb + wc*WNT + j)*16 + l15;
        float bv = bias[col];
        #pragma unroll
        for (int i=0;i<WMT;i++){
            int rbase = bm0 + (wr*WMT + i)*16 + quad*4;
            #pragma unroll
            for (int ii=0; ii<4; ii++){
                int row = rbase + ii;
                if (row < M){
                    float v = acc[i][j][ii] + bv;
                    if (RELU) v = fmaxf(v, 0.0f);
                    if (F32OUT) ((float*)C_)[(size_t)row*ldc + col] = v;
                    else        ((u16*)C_)[(size_t)row*ldc + col] = f2bf(v);
                }
            }
        }
    }
}

extern "C" void kernel_launch(void* const* d_in, const int* in_sizes, int n_in,
                              void* d_out, int out_size, void* d_ws, size_t ws_size,
                              hipStream_t stream)
{
    const float* x_paper  = (const float*)d_in[0];
    const float* x_author = (const float*)d_in[1];
    const float* w_in[22];
    for (int i=0;i<22;i++) w_in[i] = (const float*)d_in[i];
    const int* e_c1 = (const int*)d_in[22]; int nE_c1 = in_sizes[22]/2;
    const int* e_c2 = (const int*)d_in[23]; int nE_c2 = in_sizes[23]/2;
    const int* e_w1 = (const int*)d_in[24]; int nE_w1 = in_sizes[24]/2;
    const int* e_w2 = (const int*)d_in[25]; int nE_w2 = in_sizes[25]/2;
    const int* e_r1 = (const int*)d_in[26]; int nE_r1 = in_sizes[26]/2;
    const int* e_r2 = (const int*)d_in[27]; int nE_r2 = in_sizes[27]/2;
    float* out = (float*)d_out;

    // ---- workspace layout (~320 MB peak) ----
    size_t off = 0;
    auto take = [&](size_t nb)->void* {
        void* p = (char*)d_ws + off;
        off = (off + nb + 255) & ~(size_t)255;
        return p;
    };
    u16*   A1  = (u16*)take((size_t)NP_H01*768*2); // L1 A; early life: xpb|xab overlay
    u16*   xa  = (u16*)take((size_t)NA_H01*256*2); // L0 author output (bf16)
    u16*   Ap  = (u16*)take((size_t)NP_H01*384*2); // L0 paper A; later h1 overlay
    u16*   Aa  = (u16*)take((size_t)NA_H01*256*2); // L0 author A
    int*   deg    = (int*)take((size_t)SCAN_N*4);
    int*   rowptr = (int*)take((size_t)(SCAN_N+1)*4);
    int*   wp     = (int*)take((size_t)SCAN_N*4);
    int*   bsum   = (int*)take((size_t)SCAN_NBLK*4);
    int*   pool   = (int*)take((size_t)4000000*4);
    u16* Wc0p = (u16*)take((size_t)384*256*2);
    u16* Wc0a = (u16*)take((size_t)256*256*2);
    u16* Wc1  = (u16*)take((size_t)768*256*2);
    u16* Wcf  = (u16*)take((size_t)256*64*2);
    u16* Wp0p = (u16*)take((size_t)384*256*2);
    u16* Wp0a = (u16*)take((size_t)256*256*2);
    u16* Wp1  = (u16*)take((size_t)768*256*2);
    u16* Wpf  = (u16*)take((size_t)256*64*2);
    float* b0p = (float*)take(256*4);
    float* b0a = (float*)take(256*4);
    float* b1  = (float*)take(256*4);
    float* bfin= (float*)take(64*4);

    // overlays:
    u16* xpb = A1;                                   // bf16 x_paper  (NP_ALL x 128)
    u16* xab = A1 + (size_t)NP_ALL*128;              // bf16 x_author (NA_ALL x 128)
    u16* h1  = Ap;                                   // L1 hidden, Ap dead after L0 GEMM

    auto cdiv = [](long a, long b){ return (int)((a + b - 1)/b); };
    dim3 B(256);

    // ---- phase 0: zero CSR histogram ----
    hipMemsetAsync(deg, 0, (size_t)SCAN_N*4, stream);

    // ---- phase 1: weight + feature prep ----
    wcvt_k<<<cdiv(32768,256),B,0,stream>>>(Wc0p,        w_in[2], 32768);
    wcvt_k<<<cdiv(32768,256),B,0,stream>>>(Wc0p+32768,  w_in[5], 32768);
    wadd_k<<<cdiv(32768,256),B,0,stream>>>(Wc0p+65536,  w_in[4], w_in[7], 32768);
    wcvt_k<<<cdiv(32768,256),B,0,stream>>>(Wc0a,        w_in[8], 32768);
    wcvt_k<<<cdiv(32768,256),B,0,stream>>>(Wc0a+32768,  w_in[10], 32768);
    wcvt_k<<<cdiv(65536,256),B,0,stream>>>(Wc1,         w_in[11], 65536);
    wcvt_k<<<cdiv(65536,256),B,0,stream>>>(Wc1+65536,   w_in[14], 65536);
    wadd_k<<<cdiv(65536,256),B,0,stream>>>(Wc1+131072,  w_in[13], w_in[16], 65536);
    wcvt_k<<<cdiv(16384,256),B,0,stream>>>(Wcf,         w_in[20], 16384);
    bias_k<<<1,B,0,stream>>>(b0p, w_in[3],  w_in[6],  256);
    bias_k<<<1,B,0,stream>>>(b0a, w_in[9],  nullptr,  256);
    bias_k<<<1,B,0,stream>>>(b1,  w_in[12], w_in[15], 256);
    bias_k<<<1,B,0,stream>>>(bfin,w_in[21], nullptr,  64);
    repack_k<<<cdiv(12288,256),B,0,stream>>>(Wc0p, 384, 256, Wp0p);
    repack_k<<<cdiv( 8192,256),B,0,stream>>>(Wc0a, 256, 256, Wp0a);
    repack_k<<<cdiv(24576,256),B,0,stream>>>(Wc1,  768, 256, Wp1);
    repack_k<<<cdiv( 2048,256),B,0,stream>>>(Wcf,  256,  64, Wpf);
    int n2p = NP_ALL*128/2, n2a = NA_ALL*128/2;
    cvt2_k<<<cdiv(n2p,256),B,0,stream>>>((u32*)xpb, x_paper,  n2p);
    cvt2_k<<<cdiv(n2a,256),B,0,stream>>>((u32*)xab, x_author, n2a);

    // ---- phase 2: CSR build (histogram -> scan -> fill) ----
    hist_k<<<cdiv(nE_c1,256),B,0,stream>>>(e_c1+nE_c1, nE_c1, NP_H01, deg+SEG_C0);
    hist_k<<<cdiv(nE_c2,256),B,0,stream>>>(e_c2+nE_c2, nE_c2, NP_H01, deg+SEG_C0);
    hist_k<<<cdiv(nE_w1,256),B,0,stream>>>(e_w1+nE_w1, nE_w1, NP_H01, deg+SEG_W0);
    hist_k<<<cdiv(nE_w2,256),B,0,stream>>>(e_w2+nE_w2, nE_w2, NP_H01, deg+SEG_W0);
    hist_k<<<cdiv(nE_r1,256),B,0,stream>>>(e_r1+nE_r1, nE_r1, NA_H01, deg+SEG_R0);
    hist_k<<<cdiv(nE_r2,256),B,0,stream>>>(e_r2+nE_r2, nE_r2, NA_H01, deg+SEG_R0);
    hist_k<<<cdiv(nE_c1,256),B,0,stream>>>(e_c1+nE_c1, nE_c1, NP_H01, deg+SEG_C1);
    hist_k<<<cdiv(nE_w1,256),B,0,stream>>>(e_w1+nE_w1, nE_w1, NP_H01, deg+SEG_W1);
    scan1_k<<<SCAN_NBLK,B,0,stream>>>(deg, bsum);
    scan2_k<<<1,B,0,stream>>>(bsum, SCAN_NBLK);
    scan3_k<<<SCAN_NBLK,B,0,stream>>>(deg, bsum, rowptr, wp);
    fill_k<<<cdiv(nE_c1,256),B,0,stream>>>(e_c1, e_c1+nE_c1, nE_c1, NP_H01, wp+SEG_C0, pool);
    fill_k<<<cdiv(nE_c2,256),B,0,stream>>>(e_c2, e_c2+nE_c2, nE_c2, NP_H01, wp+SEG_C0, pool);
    fill_k<<<cdiv(nE_w1,256),B,0,stream>>>(e_w1, e_w1+nE_w1, nE_w1, NP_H01, wp+SEG_W0, pool);
    fill_k<<<cdiv(nE_w2,256),B,0,stream>>>(e_w2, e_w2+nE_w2, nE_w2, NP_H01, wp+SEG_W0, pool);
    fill_k<<<cdiv(nE_r1,256),B,0,stream>>>(e_r1, e_r1+nE_r1, nE_r1, NA_H01, wp+SEG_R0, pool);
    fill_k<<<cdiv(nE_r2,256),B,0,stream>>>(e_r2, e_r2+nE_r2, nE_r2, NA_H01, wp+SEG_R0, pool);
    fill_k<<<cdiv(nE_c1,256),B,0,stream>>>(e_c1, e_c1+nE_c1, nE_c1, NP_H01, wp+SEG_C1, pool);
    fill_k<<<cdiv(nE_w1,256),B,0,stream>>>(e_w1, e_w1+nE_w1, nE_w1, NP_H01, wp+SEG_W1, pool);

    // ---- phase 3: L0 gathers (build Ap, Aa) ----
    gAp_k<<<cdiv((long)NP_H01*64,256),B,0,stream>>>(xpb, xab, rowptr, pool, Ap);
    gAa_k<<<cdiv((long)NA_H01*64,256),B,0,stream>>>(xpb, xab, rowptr, pool, Aa);

    // ---- phase 4: L0 GEMMs (xpb/xab dead now; xp lands in A1 cols 512..767) ----
    {
        dim3 g(cdiv(NP_H01,128), 2);
        gemm2_k<2,2,4,4,true,false><<<g,B,0,stream>>>(Ap, 384, NP_H01, 384, Wp0p, 16, b0p, A1+512, 768);
    }
    {
        dim3 g(cdiv(NA_H01,128), 2);
        gemm2_k<2,2,4,4,true,false><<<g,B,0,stream>>>(Aa, 256, NA_H01, 256, Wp0a, 16, b0a, xa, 256);
    }

    // ---- phase 5: L1 gather (A1 cols 0..511) ----
    gA1_k<<<cdiv((long)NP_H01*64,256),B,0,stream>>>(A1+512, xa, rowptr, pool, A1);

    // ---- phase 6: L1 GEMM (h1 overlays Ap) + final linear (f32 out) ----
    {
        dim3 g(cdiv(NP_H01,128), 2);
        gemm2_k<2,2,4,4,true,false><<<g,B,0,stream>>>(A1, 768, NP_H01, 768, Wp1, 16, b1, h1, 256);
    }
    {
        dim3 g(cdiv(NP_H01,256), 1);
        gemm2_k<4,1,4,4,false,true><<<g,B,0,stream>>>(h1, 256, NP_H01, 256, Wpf, 4, bfin, out, 64);
    }
}